// Round 9
// baseline (194.464 us; speedup 1.0000x reference)
//
#include <hip/hip_runtime.h>
#include <hip/hip_bf16.h>

typedef unsigned short u16;
typedef unsigned char u8;
typedef unsigned int u32;
typedef _Float16 f16;
typedef _Float16 f16x8 __attribute__((ext_vector_type(8)));
typedef float f32x4 __attribute__((ext_vector_type(4)));
typedef unsigned int u32x4 __attribute__((ext_vector_type(4)));
typedef unsigned int u32x2 __attribute__((ext_vector_type(2)));
typedef long v2i64 __attribute__((ext_vector_type(2)));

constexpr int BATCH = 2048;
constexpr int DIM   = 512;
constexpr int NCLS  = 10000;
constexpr int NPAD  = 10240;   // 80 * 128 (zero-padded rows)

#define F_S     30.0f
#define F_COS_M 0.9800665778412416f
#define F_SIN_M 0.19866933079506122f
#define F_TH   (-0.9800665778412416f)
#define F_MM    0.03973386615901224f

#define G_AAM  256    // 16 bm x 8 xcd x 2 halves; each block owns 5 bn tiles (persistent-A)
#define G_CC   256    // 16 bm x 8 xcd x 2 halves; each block owns 2 bn tiles

static __device__ __forceinline__ float clampf(float v, float lo, float hi) {
    return fminf(fmaxf(v, lo), hi);
}
static __device__ __forceinline__ u32 pk4_fp8(float a, float b, float c, float d) {
    u32 w = __builtin_amdgcn_cvt_pk_fp8_f32(a, b, 0, false);
    w = __builtin_amdgcn_cvt_pk_fp8_f32(c, d, w, true);
    return w;
}
// async global->LDS, 16B/lane. DEST must be wave-uniform base + lane*16; SOURCE may scatter per-lane.
static __device__ __forceinline__ void glds16(const void* g, void* l) {
    __builtin_amdgcn_global_load_lds(
        (const __attribute__((address_space(1))) unsigned int*)g,
        (__attribute__((address_space(3))) unsigned int*)l, 16, 0, 0);
}
static __device__ __forceinline__ float blk_sum(float v, float* sh, int t) {
#pragma unroll
    for (int o = 32; o > 0; o >>= 1) v += __shfl_down(v, o, 64);
    __syncthreads();
    if ((t & 63) == 0) sh[t >> 6] = v;
    __syncthreads();
    return sh[0] + sh[1] + sh[2] + sh[3];
}

// ============ normalize: one WAVE per row -> fp8 e4m3, ks-interleaved rows, COALESCED stores ============
// Interleave (byte blk*64+q*16+ks*8 holds k=blk*64+ks*32+q*8) realized via lane-permute shfl,
// so global stores are lane-contiguous 8B (512B/wave). Same permutation for ALL matrices.
__global__ __launch_bounds__(256) void norm_all_kernel(const float* __restrict__ x,
                                                       const float* __restrict__ w,
                                                       const float* __restrict__ wm,
                                                       const float* __restrict__ wn,
                                                       const int* __restrict__ label,
                                                       u8* __restrict__ xnb,
                                                       u8* __restrict__ wb,
                                                       u8* __restrict__ wqb,
                                                       u8* __restrict__ wkb,
                                                       float* __restrict__ zacc) {
    const int t = threadIdx.x, lane = t & 63, wv = t >> 6;
    const int b = blockIdx.x;
    if (b < 33) zacc[b * 256 + t] = 0.f;   // zero accumulators (8448 >= 8196 used)

    const int row = b * 4 + wv;
    const float* src;
    u8* dst;
    if (row < BATCH) {
        src = x + (size_t)row * DIM;
        dst = xnb + (size_t)row * DIM;
    } else if (row < BATCH + NPAD) {
        const int r = row - BATCH;
        dst = wb + (size_t)r * DIM;
        if (r >= NCLS) {   // zero pad rows (wave-uniform)
            u32x2 z = {0, 0};
            *(u32x2*)(dst + lane * 8) = z;
            return;
        }
        src = w + (size_t)r * DIM;
    } else if (row < BATCH + NPAD + BATCH) {
        const int i = row - (BATCH + NPAD);
        src = wm + (size_t)label[i] * DIM;
        dst = wqb + (size_t)i * DIM;
    } else {
        const int i = row - (BATCH + NPAD + BATCH);
        src = wn + (size_t)label[i] * DIM;
        dst = wkb + (size_t)i * DIM;
    }
    const float4 v0 = ((const float4*)src)[lane * 2];
    const float4 v1 = ((const float4*)src)[lane * 2 + 1];
    float s = v0.x * v0.x + v0.y * v0.y + v0.z * v0.z + v0.w * v0.w
            + v1.x * v1.x + v1.y * v1.y + v1.z * v1.z + v1.w * v1.w;
#pragma unroll
    for (int o = 32; o > 0; o >>= 1) s += __shfl_xor(s, o, 64);
    const float inv = 1.0f / fmaxf(sqrtf(s), 1e-12f);
    u32 lo = pk4_fp8(v0.x * inv, v0.y * inv, v0.z * inv, v0.w * inv);
    u32 hi = pk4_fp8(v1.x * inv, v1.y * inv, v1.z * inv, v1.w * inv);
    // dst byte range [8*lane, 8*lane+8) needs source lane p's pack
    const int p = 8 * (lane >> 3) + 4 * (lane & 1) + ((lane >> 1) & 3);
    u32x2 o2;
    o2[0] = __shfl(lo, p, 64);
    o2[1] = __shfl(hi, p, 64);
    *(u32x2*)(dst + lane * 8) = o2;
}

// ============ PERSISTENT-A fused fp8 GEMM: 512 blocks (2/CU), A-tile staged ONCE ============
// A (128 rows x 512 B fp8) lives in LDS full-K with row-rotated granules (LDS[r][g]=SRC[r][(g+4r)&31],
// 64B-line aligned) -> conflict-free 8-lanes/bank-group fragment reads. Per bn-tile, only the 8 KB
// B-slice is staged per kb. Blocks [0,256)=AAM (5 bn tiles), [256,512)=CC (2 bn tiles, dual GEMM).
__global__ __launch_bounds__(256) void gemm_persist_kernel(const u8* __restrict__ A,
                                                           const u8* __restrict__ Bw,
                                                           const u8* __restrict__ Bq,
                                                           const u8* __restrict__ Bk,
                                                           const int* __restrict__ label,
                                                           float* __restrict__ sumexp,
                                                           float* __restrict__ sumlogit,
                                                           float* __restrict__ philab,
                                                           f16* __restrict__ sim,
                                                           float* __restrict__ msum,
                                                           float* __restrict__ mcnt,
                                                           float* __restrict__ ap) {
    __shared__ __align__(16) u8 sA[128 * 512];   // 64 KB full-K A tile
    __shared__ __align__(16) u8 sB[8192];        // 8 KB B slice (CC: Q=[0,4K), K=[4K,8K))
    __shared__ float red0[128];
    __shared__ float red1[128];

    const int t = threadIdx.x;
    const int lane = t & 63, wave = t >> 6;
    const int fr = lane & 15, quad = lane >> 4;
    const int slotB = quad ^ (fr & 3);               // B fragment slot (R8-verified scheme)
    const int rotA  = (quad - 4 * fr) & 31;          // A granule rotation base

    if (t < 128) { red0[t] = 0.f; red1[t] = 0.f; }

    const bool is_aam = blockIdx.x < G_AAM;
    const int c = is_aam ? blockIdx.x : (blockIdx.x - G_AAM);
    const int xcd = c & 7, g = c >> 3;               // g 0..31
    const int bm = g & 15, half = g >> 4;

    // ---- stage A tile (both roles): 16 shots x 4 KB, rotated source granules ----
    {
        const int rl = t >> 5;                       // row within 8-row shot
        const int gg = t & 31;                       // dest granule
        const int gs = (gg + 4 * rl) & 31;           // rotated source granule (64B-aligned blocks)
        const u8* abase = A + ((size_t)(bm * 128 + rl)) * 512 + gs * 16;
#pragma unroll
        for (int s = 0; s < 16; s++)
            glds16(abase + (size_t)(s * 8) * 512, &sA[s * 4096 + t * 16]);
    }

    const int srow = t >> 2;                         // 0..63, B staging row
    const int sgr  = (t & 3) ^ (srow & 3);           // swizzled B source granule

    if (is_aam) {
        // ---------------- AAM: 5 bn tiles of 128 cols ----------------
        const int wm = (wave >> 1) * 64, wn = (wave & 1) * 64;
        for (int u = 0; u < 5; u++) {
            const int bn = (half * 5 + u) * 8 + xcd;   // XCD-local columns
            f32x4 acc[4][4] = {};
            for (int kb = 0; kb < 8; kb++) {
                glds16(Bw + (size_t)(bn * 128 + srow) * 512 + kb * 64 + sgr * 16, &sB[t * 16]);
                glds16(Bw + (size_t)(bn * 128 + 64 + srow) * 512 + kb * 64 + sgr * 16, &sB[4096 + t * 16]);
                __syncthreads();
                const int gA = (4 * kb + rotA) & 31;
                v2i64 a8[4], b8[4];
#pragma unroll
                for (int f = 0; f < 4; f++) {
                    a8[f] = __builtin_bit_cast(v2i64, *(const u32x4*)&sA[(wm + f * 16 + fr) * 512 + gA * 16]);
                    b8[f] = __builtin_bit_cast(v2i64, *(const u32x4*)&sB[(wn + f * 16 + fr) * 64 + slotB * 16]);
                }
#pragma unroll
                for (int i = 0; i < 4; i++)
#pragma unroll
                    for (int j = 0; j < 4; j++) {
                        acc[i][j] = __builtin_amdgcn_mfma_f32_16x16x32_fp8_fp8(a8[i][0], b8[j][0], acc[i][j], 0, 0, 0);
                        acc[i][j] = __builtin_amdgcn_mfma_f32_16x16x32_fp8_fp8(a8[i][1], b8[j][1], acc[i][j], 0, 0, 0);
                    }
                __syncthreads();
            }
            // epilogue: Σexp(logit), Σlogit per row (logits<=30 -> fp32 safe, no max-sub)
#pragma unroll
            for (int i = 0; i < 4; i++) {
#pragma unroll
                for (int r3 = 0; r3 < 4; r3++) {
                    const int ml = wm + i * 16 + quad * 4 + r3;
                    const int mg = bm * 128 + ml;
                    const int lab = label[mg];
                    float esum = 0.f, lsum = 0.f;
#pragma unroll
                    for (int j = 0; j < 4; j++) {
                        const int ng = bn * 128 + wn + j * 16 + fr;
                        if (ng < NCLS) {
                            float cv = acc[i][j][r3];
                            float logit;
                            if (ng == lab) {
                                float sine = sqrtf(clampf(1.f - cv * cv, 0.f, 1.f));
                                float phi = cv * F_COS_M - sine * F_SIN_M;
                                float val = ((cv - F_TH) > 0.f) ? phi : (cv - F_MM);
                                logit = F_S * val;
                                philab[mg] = logit;
                            } else {
                                logit = F_S * cv;
                            }
                            esum += __expf(logit);
                            lsum += logit;
                        }
                    }
#pragma unroll
                    for (int off = 1; off < 16; off <<= 1) {
                        esum += __shfl_xor(esum, off, 64);
                        lsum += __shfl_xor(lsum, off, 64);
                    }
                    if (fr == 0) {
                        atomicAdd(&red0[ml], esum);
                        atomicAdd(&red1[ml], lsum);
                    }
                }
            }
            __syncthreads();
            if (t < 128) {
                atomicAdd(&sumexp[bm * 128 + t], red0[t]);
                atomicAdd(&sumlogit[bm * 128 + t], red1[t]);
                red0[t] = 0.f; red1[t] = 0.f;   // re-zero for next tile (8 barriers before reuse)
            }
        }
    } else {
        // ---------------- CC: 2 bn tiles of 64 cols, dual GEMM ----------------
        const int wm = (wave >> 1) * 64, wn = (wave & 1) * 32;
        u8* Qs = sB;
        u8* Ks = sB + 4096;
        for (int u = 0; u < 2; u++) {
            const int bn = (half * 2 + u) * 8 + xcd;   // 0..31
            f32x4 aq[4][2] = {};
            f32x4 ak[4][2] = {};
            for (int kb = 0; kb < 8; kb++) {
                glds16(Bq + (size_t)(bn * 64 + srow) * 512 + kb * 64 + sgr * 16, &Qs[t * 16]);
                glds16(Bk + (size_t)(bn * 64 + srow) * 512 + kb * 64 + sgr * 16, &Ks[t * 16]);
                __syncthreads();
                const int gA = (4 * kb + rotA) & 31;
                v2i64 a8[4], q8[2], k8[2];
#pragma unroll
                for (int f = 0; f < 4; f++)
                    a8[f] = __builtin_bit_cast(v2i64, *(const u32x4*)&sA[(wm + f * 16 + fr) * 512 + gA * 16]);
#pragma unroll
                for (int f = 0; f < 2; f++) {
                    q8[f] = __builtin_bit_cast(v2i64, *(const u32x4*)&Qs[(wn + f * 16 + fr) * 64 + slotB * 16]);
                    k8[f] = __builtin_bit_cast(v2i64, *(const u32x4*)&Ks[(wn + f * 16 + fr) * 64 + slotB * 16]);
                }
#pragma unroll
                for (int i = 0; i < 4; i++)
#pragma unroll
                    for (int j = 0; j < 2; j++) {
                        aq[i][j] = __builtin_amdgcn_mfma_f32_16x16x32_fp8_fp8(a8[i][0], q8[j][0], aq[i][j], 0, 0, 0);
                        aq[i][j] = __builtin_amdgcn_mfma_f32_16x16x32_fp8_fp8(a8[i][1], q8[j][1], aq[i][j], 0, 0, 0);
                        ak[i][j] = __builtin_amdgcn_mfma_f32_16x16x32_fp8_fp8(a8[i][0], k8[j][0], ak[i][j], 0, 0, 0);
                        ak[i][j] = __builtin_amdgcn_mfma_f32_16x16x32_fp8_fp8(a8[i][1], k8[j][1], ak[i][j], 0, 0, 0);
                    }
                __syncthreads();
            }
            int lab_n[2];
#pragma unroll
            for (int j = 0; j < 2; j++) lab_n[j] = label[bn * 64 + wn + j * 16 + fr];
#pragma unroll
            for (int i = 0; i < 4; i++) {
#pragma unroll
                for (int r3 = 0; r3 < 4; r3++) {
                    const int ml = wm + i * 16 + quad * 4 + r3;
                    const int mg = bm * 128 + ml;
                    const int lm = label[mg];
                    float ms = 0.f, mc = 0.f;
#pragma unroll
                    for (int j = 0; j < 2; j++) {
                        const int ng = bn * 64 + wn + j * 16 + fr;
                        float s = aq[i][j][r3] * ak[i][j][r3];
                        sim[(size_t)mg * BATCH + ng] = (f16)s;
                        if (lab_n[j] == lm) { ms += s; mc += 1.f; }
                        if (mg == ng) ap[mg] = s;   // unique writer; read next dispatch
                    }
#pragma unroll
                    for (int off = 1; off < 16; off <<= 1) {
                        ms += __shfl_xor(ms, off, 64);
                        mc += __shfl_xor(mc, off, 64);
                    }
                    if (fr == 0) {
                        atomicAdd(&red0[ml], ms);
                        atomicAdd(&red1[ml], mc);
                    }
                }
            }
            __syncthreads();
            if (t < 128) {
                atomicAdd(&msum[bm * 128 + t], red0[t]);
                atomicAdd(&mcnt[bm * 128 + t], red1[t]);
                red0[t] = 0.f; red1[t] = 0.f;
            }
        }
    }
}

// ============ CC pass 2 + finalize (fp16 sim; atomics-only ticket, no fences) ============
__global__ __launch_bounds__(256) void cc_pass2_kernel(const f16* __restrict__ sim,
                                                       const int* __restrict__ label,
                                                       const float* __restrict__ msum,
                                                       const float* __restrict__ mcnt,
                                                       const float* __restrict__ ap,
                                                       const float* __restrict__ sumexp,
                                                       const float* __restrict__ sumlogit,
                                                       const float* __restrict__ philab,
                                                       float* __restrict__ zn,
                                                       float* __restrict__ zneg,
                                                       float* __restrict__ accA,
                                                       unsigned* __restrict__ tick,
                                                       float* __restrict__ out) {
    __shared__ __align__(16) float cam_s[BATCH];
    __shared__ __align__(16) float sam_s[BATCH];
    __shared__ float sh[4];
    const int t = threadIdx.x, b = blockIdx.x;

    for (int j = t; j < BATCH; j += 256) {
        float cam = clampf(msum[j] / mcnt[j], 0.f, 1.f);   // mcnt >= 1 (diagonal)
        cam_s[j] = cam;
        sam_s[j] = sqrtf(clampf(1.f - cam, 0.f, 1.f));
    }
    __syncthreads();

    float acc = 0.f;
#pragma unroll
    for (int row = 0; row < 4; row++) {
        const int i = b * 4 + row;
        const int li = label[i];
        const f16x8 v = ((const f16x8*)(sim + (size_t)i * BATCH))[t];   // j = t*8+e
        const int4 l0 = ((const int4*)label)[t * 2];
        const int4 l1 = ((const int4*)label)[t * 2 + 1];
        const f32x4 ca0 = ((const f32x4*)cam_s)[t * 2];
        const f32x4 ca1 = ((const f32x4*)cam_s)[t * 2 + 1];
        const f32x4 sa0 = ((const f32x4*)sam_s)[t * 2];
        const f32x4 sa1 = ((const f32x4*)sam_s)[t * 2 + 1];
#pragma unroll
        for (int e = 0; e < 8; e++) {
            const int lj = (e < 4) ? ((const int*)&l0)[e] : ((const int*)&l1)[e - 4];
            if (lj != li) {
                float can = clampf((float)v[e], 0.f, 1.f);
                float caj = (e < 4) ? ca0[e] : ca1[e - 4];
                float saj = (e < 4) ? sa0[e] : sa1[e - 4];
                float san = sqrtf(clampf(1.f - can, 0.f, 1.f));
                float pns = san * caj + can * saj;            // column-j broadcast
                float pnc = sqrtf(clampf(1.f - pns, 0.f, 1.f));
                acc += __expf(pns * F_COS_M - pnc * F_SIN_M);
            }
        }
    }
    acc = blk_sum(acc, sh, t);

    if (t == 0) {
        float apart = 0.f, epart = 0.f;
#pragma unroll
        for (int row = 0; row < 4; row++) {
            const int rr = b * 4 + row;
            float lse = logf(sumexp[rr]);
            apart += 0.9f * (philab[rr] - lse) + 1e-5f * (sumlogit[rr] - (float)NCLS * lse);
            float cam = cam_s[rr], sam = sam_s[rr];
            float cap = clampf(ap[rr], 0.f, 1.f);
            float sap = sqrtf(clampf(1.f - cap, 0.f, 1.f));
            float ppc = cap * cam - sap * sam;
            float pps = sqrtf(clampf(1.f - ppc, 0.f, 1.f));
            epart += __expf(1.f - (ppc * F_COS_M - pps * F_SIN_M));
        }
        atomicAdd(zn, acc);
        atomicAdd(accA, apart);
        atomicAdd(zneg, epart);
        unsigned old = __hip_atomic_fetch_add(tick, 1u, __ATOMIC_ACQ_REL, __HIP_MEMORY_SCOPE_AGENT);
        if (old == 511u) {   // last block
            float znv = __hip_atomic_load(zn,   __ATOMIC_RELAXED, __HIP_MEMORY_SCOPE_AGENT);
            float aav = __hip_atomic_load(accA, __ATOMIC_RELAXED, __HIP_MEMORY_SCOPE_AGENT);
            float zgv = __hip_atomic_load(zneg, __ATOMIC_RELAXED, __HIP_MEMORY_SCOPE_AGENT);
            float aam = -aav / (float)BATCH;
            float z = logf(znv) + logf(zgv);
            float cc = (z > 0.f) ? (z + log1pf(__expf(-z))) : log1pf(__expf(z));
            out[0] = aam + cc;
        }
    }
}

extern "C" void kernel_launch(void* const* d_in, const int* in_sizes, int n_in,
                              void* d_out, int out_size, void* d_ws, size_t ws_size,
                              hipStream_t stream) {
    const float* x        = (const float*)d_in[0];
    const int*   label    = (const int*)d_in[1];
    const float* weight   = (const float*)d_in[2];
    const float* weight_m = (const float*)d_in[3];
    const float* weight_n = (const float*)d_in[4];
    float* out = (float*)d_out;
    char* ws = (char*)d_ws;

    // compact ws (~17 MB): fp8 operands + fp16 sim + misc
    const size_t o_xnb  = 0;                                   // 1 MB
    const size_t o_wb   = o_xnb + (size_t)BATCH * DIM;         // 5.24 MB
    const size_t o_wqb  = o_wb  + (size_t)NPAD * DIM;          // 1 MB
    const size_t o_wkb  = o_wqb + (size_t)BATCH * DIM;         // 1 MB
    const size_t o_sim  = o_wkb + (size_t)BATCH * DIM;         // 8.39 MB (fp16)
    const size_t o_misc = o_sim + (size_t)BATCH * BATCH * 2;

    u8* xnb = (u8*)(ws + o_xnb);
    u8* wb  = (u8*)(ws + o_wb);
    u8* wqb = (u8*)(ws + o_wqb);
    u8* wkb = (u8*)(ws + o_wkb);
    f16* sim = (f16*)(ws + o_sim);
    float* mf  = (float*)(ws + o_misc);

    // zeroed by norm_all (33*256 = 8448 floats)
    float* sumexp   = mf;               // 2048
    float* sumlogit = mf + 2048;        // 2048
    float* msum     = mf + 4096;        // 2048
    float* mcnt     = mf + 6144;        // 2048
    float* zn       = mf + 8192;        // 1
    float* zneg     = mf + 8193;        // 1
    float* accA     = mf + 8194;        // 1
    unsigned* tick  = (unsigned*)(mf + 8195);
    // non-zeroed (fully overwritten every launch)
    float* philab  = mf + 8448;         // 2048
    float* ap      = mf + 10496;        // 2048

    norm_all_kernel<<<(BATCH + NPAD + 2 * BATCH) / 4, 256, 0, stream>>>(
        x, weight, weight_m, weight_n, label, xnb, wb, wqb, wkb, mf);

    gemm_persist_kernel<<<G_AAM + G_CC, 256, 0, stream>>>(
        xnb, wb, wqb, wkb, label,
        sumexp, sumlogit, philab, sim, msum, mcnt, ap);

    cc_pass2_kernel<<<512, 256, 0, stream>>>(
        sim, label, msum, mcnt, ap,
        sumexp, sumlogit, philab, zn, zneg, accA, tick, out);
}

// Round 10
// 183.074 us; speedup vs baseline: 1.0622x; 1.0622x over previous
//
#include <hip/hip_runtime.h>
#include <hip/hip_bf16.h>

typedef unsigned short u16;
typedef unsigned char u8;
typedef unsigned int u32;
typedef _Float16 f16;
typedef _Float16 f16x8 __attribute__((ext_vector_type(8)));
typedef float f32x4 __attribute__((ext_vector_type(4)));
typedef unsigned int u32x4 __attribute__((ext_vector_type(4)));
typedef unsigned int u32x2 __attribute__((ext_vector_type(2)));
typedef long v2i64 __attribute__((ext_vector_type(2)));

constexpr int BATCH = 2048;
constexpr int DIM   = 512;
constexpr int NCLS  = 10000;
constexpr int NPAD  = 10240;   // 80 * 128 (zero-padded rows)

#define F_S     30.0f
#define F_COS_M 0.9800665778412416f
#define F_SIN_M 0.19866933079506122f
#define F_TH   (-0.9800665778412416f)
#define F_MM    0.03973386615901224f

#define G_AAM  1280   // 16 bm x 80 bn (128x128 tiles)
#define G_CC    512   // 16 bm x 32 bn (128x64 tiles)

static __device__ __forceinline__ float clampf(float v, float lo, float hi) {
    return fminf(fmaxf(v, lo), hi);
}
static __device__ __forceinline__ u32 pk4_fp8(float a, float b, float c, float d) {
    u32 w = __builtin_amdgcn_cvt_pk_fp8_f32(a, b, 0, false);
    w = __builtin_amdgcn_cvt_pk_fp8_f32(c, d, w, true);
    return w;
}
// async global->LDS, 16B/lane. DEST must be wave-uniform base + lane*16; SOURCE may scatter per-lane.
static __device__ __forceinline__ void glds16(const void* g, void* l) {
    __builtin_amdgcn_global_load_lds(
        (const __attribute__((address_space(1))) unsigned int*)g,
        (__attribute__((address_space(3))) unsigned int*)l, 16, 0, 0);
}
static __device__ __forceinline__ float blk_sum(float v, float* sh, int t) {
#pragma unroll
    for (int o = 32; o > 0; o >>= 1) v += __shfl_down(v, o, 64);
    __syncthreads();
    if ((t & 63) == 0) sh[t >> 6] = v;
    __syncthreads();
    return sh[0] + sh[1] + sh[2] + sh[3];
}

// ============ normalize: one WAVE per row -> fp8 e4m3, ks-interleaved rows, COALESCED stores ============
// Byte blk*64+q*16+ks*8 holds k=blk*64+ks*32+q*8 (same permutation for ALL matrices -> dot invariant),
// realized via lane-permute shfl so stores stay lane-contiguous.
__global__ __launch_bounds__(256) void norm_all_kernel(const float* __restrict__ x,
                                                       const float* __restrict__ w,
                                                       const float* __restrict__ wm,
                                                       const float* __restrict__ wn,
                                                       const int* __restrict__ label,
                                                       u8* __restrict__ xnb,
                                                       u8* __restrict__ wb,
                                                       u8* __restrict__ wqb,
                                                       u8* __restrict__ wkb,
                                                       float* __restrict__ zacc) {
    const int t = threadIdx.x, lane = t & 63, wv = t >> 6;
    const int b = blockIdx.x;
    if (b < 33) zacc[b * 256 + t] = 0.f;   // zero accumulators (8448 >= 8196 used)

    const int row = b * 4 + wv;
    const float* src;
    u8* dst;
    if (row < BATCH) {
        src = x + (size_t)row * DIM;
        dst = xnb + (size_t)row * DIM;
    } else if (row < BATCH + NPAD) {
        const int r = row - BATCH;
        dst = wb + (size_t)r * DIM;
        if (r >= NCLS) {   // zero pad rows (wave-uniform)
            u32x2 z = {0, 0};
            *(u32x2*)(dst + lane * 8) = z;
            return;
        }
        src = w + (size_t)r * DIM;
    } else if (row < BATCH + NPAD + BATCH) {
        const int i = row - (BATCH + NPAD);
        src = wm + (size_t)label[i] * DIM;
        dst = wqb + (size_t)i * DIM;
    } else {
        const int i = row - (BATCH + NPAD + BATCH);
        src = wn + (size_t)label[i] * DIM;
        dst = wkb + (size_t)i * DIM;
    }
    const float4 v0 = ((const float4*)src)[lane * 2];
    const float4 v1 = ((const float4*)src)[lane * 2 + 1];
    float s = v0.x * v0.x + v0.y * v0.y + v0.z * v0.z + v0.w * v0.w
            + v1.x * v1.x + v1.y * v1.y + v1.z * v1.z + v1.w * v1.w;
#pragma unroll
    for (int o = 32; o > 0; o >>= 1) s += __shfl_xor(s, o, 64);
    const float inv = 1.0f / fmaxf(sqrtf(s), 1e-12f);
    u32 lo = pk4_fp8(v0.x * inv, v0.y * inv, v0.z * inv, v0.w * inv);
    u32 hi = pk4_fp8(v1.x * inv, v1.y * inv, v1.z * inv, v1.w * inv);
    const int p = 8 * (lane >> 3) + 4 * (lane & 1) + ((lane >> 1) & 3);
    u32x2 o2;
    o2[0] = __shfl(lo, p, 64);
    o2[1] = __shfl(hi, p, 64);
    *(u32x2*)(dst + lane * 8) = o2;
}

// ============ FUSED fp8 GEMM (R8 frame, BK=128): [0,1280)=AAM 128x128, [1280,1792)=CC 128x64 ============
// 4 kb iterations x 2 barriers (vs 8x2 at BK=64); 8 glds in flight per barrier. LDS rows are
// 128 B so bank-group = slot (row*8 = 0 mod 8); store LDS[r][g]=SRC[r][g^(r&7)], read slot
// ((blkr<<2)|quad)^(fr&7) -> 8 lanes/bank-group, balanced.
__global__ __launch_bounds__(256) void gemm_fused_kernel(const u8* __restrict__ A,
                                                         const u8* __restrict__ Bw,
                                                         const u8* __restrict__ Bq,
                                                         const u8* __restrict__ Bk,
                                                         const int* __restrict__ label,
                                                         float* __restrict__ sumexp,
                                                         float* __restrict__ sumlogit,
                                                         float* __restrict__ philab,
                                                         f16* __restrict__ sim,
                                                         float* __restrict__ msum,
                                                         float* __restrict__ mcnt,
                                                         float* __restrict__ ap) {
    __shared__ __align__(16) u8 sA[128 * 128];   // 16 KB
    __shared__ __align__(16) u8 sB[128 * 128];   // 16 KB (CC: Qs=[0,8K), Ks=[8K,16K))
    __shared__ float red0[128];
    __shared__ float red1[128];

    const int t = threadIdx.x;
    const int lane = t & 63, wave = t >> 6;
    const int fr = lane & 15, quad = lane >> 4;
    const int swz = fr & 7;

    if (t < 128) { red0[t] = 0.f; red1[t] = 0.f; }

    const int srow = t >> 3;                     // 0..31 (+32s per shot)
    const int sgs  = (t & 7) ^ (srow & 7);       // swizzled source granule (shot rows keep row%8)

    if (blockIdx.x < G_AAM) {
        // ---------------- AAM: 128x128 tile, BK=128, 4 kb ----------------
        const int flat = blockIdx.x;
        const int xcd = flat & 7, r = flat >> 3;
        const int bm = r & 15;
        const int bn = (r >> 4) * 8 + xcd;       // 10 bn per xcd -> per-XCD L2-resident

        const int wm = (wave >> 1) * 64, wn = (wave & 1) * 64;
        const u8* ag = A  + (size_t)(bm * 128 + srow) * DIM + sgs * 16;
        const u8* bg = Bw + (size_t)(bn * 128 + srow) * DIM + sgs * 16;

        f32x4 acc[4][4] = {};

        for (int kb = 0; kb < 4; kb++) {
            const int ko = kb * 128;
#pragma unroll
            for (int s = 0; s < 4; s++) {
                glds16(ag + (size_t)(s * 32) * DIM + ko, &sA[s * 4096 + t * 16]);
                glds16(bg + (size_t)(s * 32) * DIM + ko, &sB[s * 4096 + t * 16]);
            }
            __syncthreads();
#pragma unroll
            for (int blkr = 0; blkr < 2; blkr++) {
                const int slot = ((blkr << 2) | quad) ^ swz;
                v2i64 a8[4], b8[4];
#pragma unroll
                for (int f = 0; f < 4; f++) {
                    a8[f] = __builtin_bit_cast(v2i64, *(const u32x4*)&sA[(wm + f * 16 + fr) * 128 + slot * 16]);
                    b8[f] = __builtin_bit_cast(v2i64, *(const u32x4*)&sB[(wn + f * 16 + fr) * 128 + slot * 16]);
                }
#pragma unroll
                for (int i = 0; i < 4; i++)
#pragma unroll
                    for (int j = 0; j < 4; j++) {
                        acc[i][j] = __builtin_amdgcn_mfma_f32_16x16x32_fp8_fp8(a8[i][0], b8[j][0], acc[i][j], 0, 0, 0);
                        acc[i][j] = __builtin_amdgcn_mfma_f32_16x16x32_fp8_fp8(a8[i][1], b8[j][1], acc[i][j], 0, 0, 0);
                    }
            }
            __syncthreads();
        }

        // Epilogue: per-row partial Σexp(logit), Σlogit (logits<=30 -> fp32 safe, no max-sub)
#pragma unroll
        for (int i = 0; i < 4; i++) {
#pragma unroll
            for (int r3 = 0; r3 < 4; r3++) {
                const int ml = wm + i * 16 + quad * 4 + r3;
                const int mg = bm * 128 + ml;
                const int lab = label[mg];
                float esum = 0.f, lsum = 0.f;
#pragma unroll
                for (int j = 0; j < 4; j++) {
                    const int ng = bn * 128 + wn + j * 16 + fr;
                    if (ng < NCLS) {
                        float cv = acc[i][j][r3];
                        float logit;
                        if (ng == lab) {
                            float sine = sqrtf(clampf(1.f - cv * cv, 0.f, 1.f));
                            float phi = cv * F_COS_M - sine * F_SIN_M;
                            float val = ((cv - F_TH) > 0.f) ? phi : (cv - F_MM);
                            logit = F_S * val;
                            philab[mg] = logit;
                        } else {
                            logit = F_S * cv;
                        }
                        esum += __expf(logit);
                        lsum += logit;
                    }
                }
#pragma unroll
                for (int off = 1; off < 16; off <<= 1) {
                    esum += __shfl_xor(esum, off, 64);
                    lsum += __shfl_xor(lsum, off, 64);
                }
                if (fr == 0) {
                    atomicAdd(&red0[ml], esum);
                    atomicAdd(&red1[ml], lsum);
                }
            }
        }
        __syncthreads();
        if (t < 128) {
            atomicAdd(&sumexp[bm * 128 + t], red0[t]);
            atomicAdd(&sumlogit[bm * 128 + t], red1[t]);
        }
    } else {
        // ---------------- CC: dual GEMM, 128x64 tile, BK=128, 4 kb ----------------
        const int c = blockIdx.x - G_AAM;
        const int xcd = c & 7, r = c >> 3;
        const int bm = r & 15;
        const int bn = (r >> 4) * 8 + xcd;       // 0..31

        const int wm = (wave >> 1) * 64, wn = (wave & 1) * 32;
        u8* Qs = sB;
        u8* Ks = sB + 8192;

        const u8* ag = A  + (size_t)(bm * 128 + srow) * DIM + sgs * 16;
        const u8* qg = Bq + (size_t)(bn * 64 + srow) * DIM + sgs * 16;
        const u8* kg = Bk + (size_t)(bn * 64 + srow) * DIM + sgs * 16;

        f32x4 aq[4][2] = {};
        f32x4 ak[4][2] = {};

        for (int kb = 0; kb < 4; kb++) {
            const int ko = kb * 128;
#pragma unroll
            for (int s = 0; s < 4; s++)
                glds16(ag + (size_t)(s * 32) * DIM + ko, &sA[s * 4096 + t * 16]);
#pragma unroll
            for (int s = 0; s < 2; s++) {
                glds16(qg + (size_t)(s * 32) * DIM + ko, &Qs[s * 4096 + t * 16]);
                glds16(kg + (size_t)(s * 32) * DIM + ko, &Ks[s * 4096 + t * 16]);
            }
            __syncthreads();
#pragma unroll
            for (int blkr = 0; blkr < 2; blkr++) {
                const int slot = ((blkr << 2) | quad) ^ swz;
                v2i64 a8[4], q8[2], k8[2];
#pragma unroll
                for (int f = 0; f < 4; f++)
                    a8[f] = __builtin_bit_cast(v2i64, *(const u32x4*)&sA[(wm + f * 16 + fr) * 128 + slot * 16]);
#pragma unroll
                for (int f = 0; f < 2; f++) {
                    q8[f] = __builtin_bit_cast(v2i64, *(const u32x4*)&Qs[(wn + f * 16 + fr) * 128 + slot * 16]);
                    k8[f] = __builtin_bit_cast(v2i64, *(const u32x4*)&Ks[(wn + f * 16 + fr) * 128 + slot * 16]);
                }
#pragma unroll
                for (int i = 0; i < 4; i++)
#pragma unroll
                    for (int j = 0; j < 2; j++) {
                        aq[i][j] = __builtin_amdgcn_mfma_f32_16x16x32_fp8_fp8(a8[i][0], q8[j][0], aq[i][j], 0, 0, 0);
                        aq[i][j] = __builtin_amdgcn_mfma_f32_16x16x32_fp8_fp8(a8[i][1], q8[j][1], aq[i][j], 0, 0, 0);
                        ak[i][j] = __builtin_amdgcn_mfma_f32_16x16x32_fp8_fp8(a8[i][0], k8[j][0], ak[i][j], 0, 0, 0);
                        ak[i][j] = __builtin_amdgcn_mfma_f32_16x16x32_fp8_fp8(a8[i][1], k8[j][1], ak[i][j], 0, 0, 0);
                    }
            }
            __syncthreads();
        }

        int lab_n[2];
#pragma unroll
        for (int j = 0; j < 2; j++) lab_n[j] = label[bn * 64 + wn + j * 16 + fr];

#pragma unroll
        for (int i = 0; i < 4; i++) {
#pragma unroll
            for (int r3 = 0; r3 < 4; r3++) {
                const int ml = wm + i * 16 + quad * 4 + r3;
                const int mg = bm * 128 + ml;
                const int lm = label[mg];
                float ms = 0.f, mc = 0.f;
#pragma unroll
                for (int j = 0; j < 2; j++) {
                    const int ng = bn * 64 + wn + j * 16 + fr;
                    float s = aq[i][j][r3] * ak[i][j][r3];
                    sim[(size_t)mg * BATCH + ng] = (f16)s;
                    if (lab_n[j] == lm) { ms += s; mc += 1.f; }
                    if (mg == ng) ap[mg] = s;   // unique writer; read next dispatch
                }
#pragma unroll
                for (int off = 1; off < 16; off <<= 1) {
                    ms += __shfl_xor(ms, off, 64);
                    mc += __shfl_xor(mc, off, 64);
                }
                if (fr == 0) {
                    atomicAdd(&red0[ml], ms);
                    atomicAdd(&red1[ml], mc);
                }
            }
        }
        __syncthreads();
        if (t < 128) {
            atomicAdd(&msum[bm * 128 + t], red0[t]);
            atomicAdd(&mcnt[bm * 128 + t], red1[t]);
        }
    }
}

// ============ CC pass 2 + finalize (fp16 sim; atomics-only ticket, no fences) ============
__global__ __launch_bounds__(256) void cc_pass2_kernel(const f16* __restrict__ sim,
                                                       const int* __restrict__ label,
                                                       const float* __restrict__ msum,
                                                       const float* __restrict__ mcnt,
                                                       const float* __restrict__ ap,
                                                       const float* __restrict__ sumexp,
                                                       const float* __restrict__ sumlogit,
                                                       const float* __restrict__ philab,
                                                       float* __restrict__ zn,
                                                       float* __restrict__ zneg,
                                                       float* __restrict__ accA,
                                                       unsigned* __restrict__ tick,
                                                       float* __restrict__ out) {
    __shared__ __align__(16) float cam_s[BATCH];
    __shared__ __align__(16) float sam_s[BATCH];
    __shared__ float sh[4];
    const int t = threadIdx.x, b = blockIdx.x;

    for (int j = t; j < BATCH; j += 256) {
        float cam = clampf(msum[j] / mcnt[j], 0.f, 1.f);   // mcnt >= 1 (diagonal)
        cam_s[j] = cam;
        sam_s[j] = sqrtf(clampf(1.f - cam, 0.f, 1.f));
    }
    __syncthreads();

    float acc = 0.f;
#pragma unroll
    for (int row = 0; row < 4; row++) {
        const int i = b * 4 + row;
        const int li = label[i];
        const f16x8 v = ((const f16x8*)(sim + (size_t)i * BATCH))[t];   // j = t*8+e
        const int4 l0 = ((const int4*)label)[t * 2];
        const int4 l1 = ((const int4*)label)[t * 2 + 1];
        const f32x4 ca0 = ((const f32x4*)cam_s)[t * 2];
        const f32x4 ca1 = ((const f32x4*)cam_s)[t * 2 + 1];
        const f32x4 sa0 = ((const f32x4*)sam_s)[t * 2];
        const f32x4 sa1 = ((const f32x4*)sam_s)[t * 2 + 1];
#pragma unroll
        for (int e = 0; e < 8; e++) {
            const int lj = (e < 4) ? ((const int*)&l0)[e] : ((const int*)&l1)[e - 4];
            if (lj != li) {
                float can = clampf((float)v[e], 0.f, 1.f);
                float caj = (e < 4) ? ca0[e] : ca1[e - 4];
                float saj = (e < 4) ? sa0[e] : sa1[e - 4];
                float san = sqrtf(clampf(1.f - can, 0.f, 1.f));
                float pns = san * caj + can * saj;            // column-j broadcast
                float pnc = sqrtf(clampf(1.f - pns, 0.f, 1.f));
                acc += __expf(pns * F_COS_M - pnc * F_SIN_M);
            }
        }
    }
    acc = blk_sum(acc, sh, t);

    if (t == 0) {
        float apart = 0.f, epart = 0.f;
#pragma unroll
        for (int row = 0; row < 4; row++) {
            const int rr = b * 4 + row;
            float lse = logf(sumexp[rr]);
            apart += 0.9f * (philab[rr] - lse) + 1e-5f * (sumlogit[rr] - (float)NCLS * lse);
            float cam = cam_s[rr], sam = sam_s[rr];
            float cap = clampf(ap[rr], 0.f, 1.f);
            float sap = sqrtf(clampf(1.f - cap, 0.f, 1.f));
            float ppc = cap * cam - sap * sam;
            float pps = sqrtf(clampf(1.f - ppc, 0.f, 1.f));
            epart += __expf(1.f - (ppc * F_COS_M - pps * F_SIN_M));
        }
        atomicAdd(zn, acc);
        atomicAdd(accA, apart);
        atomicAdd(zneg, epart);
        unsigned old = __hip_atomic_fetch_add(tick, 1u, __ATOMIC_ACQ_REL, __HIP_MEMORY_SCOPE_AGENT);
        if (old == 511u) {   // last block
            float znv = __hip_atomic_load(zn,   __ATOMIC_RELAXED, __HIP_MEMORY_SCOPE_AGENT);
            float aav = __hip_atomic_load(accA, __ATOMIC_RELAXED, __HIP_MEMORY_SCOPE_AGENT);
            float zgv = __hip_atomic_load(zneg, __ATOMIC_RELAXED, __HIP_MEMORY_SCOPE_AGENT);
            float aam = -aav / (float)BATCH;
            float z = logf(znv) + logf(zgv);
            float cc = (z > 0.f) ? (z + log1pf(__expf(-z))) : log1pf(__expf(z));
            out[0] = aam + cc;
        }
    }
}

extern "C" void kernel_launch(void* const* d_in, const int* in_sizes, int n_in,
                              void* d_out, int out_size, void* d_ws, size_t ws_size,
                              hipStream_t stream) {
    const float* x        = (const float*)d_in[0];
    const int*   label    = (const int*)d_in[1];
    const float* weight   = (const float*)d_in[2];
    const float* weight_m = (const float*)d_in[3];
    const float* weight_n = (const float*)d_in[4];
    float* out = (float*)d_out;
    char* ws = (char*)d_ws;

    // compact ws (~17 MB): fp8 operands + fp16 sim + misc
    const size_t o_xnb  = 0;                                   // 1 MB
    const size_t o_wb   = o_xnb + (size_t)BATCH * DIM;         // 5.24 MB
    const size_t o_wqb  = o_wb  + (size_t)NPAD * DIM;          // 1 MB
    const size_t o_wkb  = o_wqb + (size_t)BATCH * DIM;         // 1 MB
    const size_t o_sim  = o_wkb + (size_t)BATCH * DIM;         // 8.39 MB (fp16)
    const size_t o_misc = o_sim + (size_t)BATCH * BATCH * 2;

    u8* xnb = (u8*)(ws + o_xnb);
    u8* wb  = (u8*)(ws + o_wb);
    u8* wqb = (u8*)(ws + o_wqb);
    u8* wkb = (u8*)(ws + o_wkb);
    f16* sim = (f16*)(ws + o_sim);
    float* mf  = (float*)(ws + o_misc);

    // zeroed by norm_all (33*256 = 8448 floats)
    float* sumexp   = mf;               // 2048
    float* sumlogit = mf + 2048;        // 2048
    float* msum     = mf + 4096;        // 2048
    float* mcnt     = mf + 6144;        // 2048
    float* zn       = mf + 8192;        // 1
    float* zneg     = mf + 8193;        // 1
    float* accA     = mf + 8194;        // 1
    unsigned* tick  = (unsigned*)(mf + 8195);
    // non-zeroed (fully overwritten every launch)
    float* philab  = mf + 8448;         // 2048
    float* ap      = mf + 10496;        // 2048

    norm_all_kernel<<<(BATCH + NPAD + 2 * BATCH) / 4, 256, 0, stream>>>(
        x, weight, weight_m, weight_n, label, xnb, wb, wqb, wkb, mf);

    gemm_fused_kernel<<<G_AAM + G_CC, 256, 0, stream>>>(
        xnb, wb, wqb, wkb, label,
        sumexp, sumlogit, philab, sim, msum, mcnt, ap);

    cc_pass2_kernel<<<512, 256, 0, stream>>>(
        sim, label, msum, mcnt, ap,
        sumexp, sumlogit, philab, zn, zneg, accA, tick, out);
}